// Round 16
// baseline (1473.626 us; speedup 1.0000x reference)
//
#include <hip/hip_runtime.h>
#include <hip/hip_bf16.h>
#include <cstdint>

#define DEV __device__ __forceinline__

typedef __bf16 bf16x8 __attribute__((ext_vector_type(8)));
typedef float f32x4 __attribute__((ext_vector_type(4)));
typedef unsigned short u16;
typedef u16 u16x8 __attribute__((ext_vector_type(8)));
typedef u16 u16x4 __attribute__((ext_vector_type(4)));
typedef uint32_t u32x2 __attribute__((ext_vector_type(2)));
typedef uint32_t u32x4 __attribute__((ext_vector_type(4)));

DEV u16 f2bf(float f) {
  union { float f; uint32_t u; } a; a.f = f;
  uint32_t u = a.u + 0x7fffu + ((a.u >> 16) & 1u);
  return (u16)(u >> 16);
}
DEV float b2f(u16 v) {
  union { uint32_t u; float f; } a; a.u = ((uint32_t)v) << 16;
  return a.f;
}

DEV float fexp2(float x) {
#if __has_builtin(__builtin_amdgcn_exp2f)
  return __builtin_amdgcn_exp2f(x);
#else
  return __expf(x * 0.69314718056f);
#endif
}

DEV uint32_t cvtpk(float lo, float hi) {
  uint32_t r;
  asm("v_cvt_pk_bf16_f32 %0, %1, %2" : "=v"(r) : "v"(lo), "v"(hi));
  return r;
}

DEV void gload16(const void* g, void* lds) {
  __builtin_amdgcn_global_load_lds((__attribute__((address_space(1))) void*)g,
                                   (__attribute__((address_space(3))) void*)lds,
                                   16, 0, 0);
}

// ---------------- weight convert + transpose: dst[n][k] = bf16(src[k][n]) ----
// Tiles of 64 output rows (n) x 128 k -> each output-row write is 256B (one
// full HBM sector, no RMW amplification). NT loads + stores.
struct TMat { const float* src; u16* dst; int K; int N; int t0; };
struct TArgs { TMat m[26]; int nmat; };

__global__ __launch_bounds__(256) void transpose_all(TArgs args) {
  __shared__ float tile[128][65];   // [k][n], +1 pad
  const int bid = blockIdx.x;
  int i = 0;
  #pragma unroll 1
  for (int t = 1; t < args.nmat; ++t) if (bid >= args.m[t].t0) i = t;
  const TMat mm = args.m[i];
  const int tid = threadIdx.x;
  const int tix = bid - mm.t0;
  const int ntx = mm.N >> 6;
  const int n0 = (tix % ntx) << 6, k0 = (tix / ntx) << 7;   // 64 n x 128 k
  // load: 128 k-rows x 64 floats; thread = (row tid>>4 (+16p), col4 (tid&15)*4)
  const int lr = tid >> 4, lc4 = (tid & 15) << 2;
  #pragma unroll
  for (int p = 0; p < 8; ++p) {
    const int r = lr + (p << 4);
    f32x4 v = __builtin_nontemporal_load(
        (const f32x4*)(mm.src + (size_t)(k0 + r) * mm.N + n0 + lc4));
    *(f32x4*)&tile[r][lc4] = v;
  }
  __syncthreads();
  // store: 64 n-rows x 128 bf16 (256B/row); 16 lanes/row x 16B, 4 passes
  const int ks8 = (tid & 15) << 3;
  #pragma unroll
  for (int p = 0; p < 4; ++p) {
    const int n = (tid >> 4) + (p << 4);
    float v[8];
    #pragma unroll
    for (int u = 0; u < 8; ++u) v[u] = tile[ks8 + u][n];
    u32x4 o;
    o[0] = cvtpk(v[0], v[1]); o[1] = cvtpk(v[2], v[3]);
    o[2] = cvtpk(v[4], v[5]); o[3] = cvtpk(v[6], v[7]);
    __builtin_nontemporal_store(
        o, (u32x4*)(mm.dst + (size_t)(n0 + n) * mm.K + k0 + ks8));
  }
}

// ---------------- fp32 -> bf16 convert (x_in -> xb) --------------------------
__global__ __launch_bounds__(256) void f2b_kernel(const f32x4* __restrict__ in,
                                                  u32x4* __restrict__ out, int n8) {
  const int i = blockIdx.x * 256 + threadIdx.x;
  if (i >= n8) return;
  f32x4 a = __builtin_nontemporal_load(in + 2 * i);
  f32x4 b = __builtin_nontemporal_load(in + 2 * i + 1);
  u32x4 o;
  o[0] = cvtpk(a[0], a[1]); o[1] = cvtpk(a[2], a[3]);
  o[2] = cvtpk(b[0], b[1]); o[3] = cvtpk(b[2], b[3]);
  __builtin_nontemporal_store(o, out + i);
}

// ---------------- LayerNorm: bf16 in -> bf16 out, XCD-aligned tokens --------
__global__ __launch_bounds__(256) void ln_kernel(const u16* __restrict__ x,
                                                 const float* __restrict__ sc,
                                                 const float* __restrict__ bi,
                                                 u16* __restrict__ y, int Mtok) {
  const int bid = blockIdx.x;
  const int tok = ((bid & 7) << 10) + ((bid >> 3) << 2) + (threadIdx.x >> 6);
  const int l = threadIdx.x & 63;
  if (tok >= Mtok) return;
  const u16* row = x + (size_t)tok * 768;
  u16x8 v0 = *(const u16x8*)(row + l * 8);          // cols l*8 .. +7
  u16x4 v1 = *(const u16x4*)(row + 512 + l * 4);    // cols 512+l*4 .. +3
  float f[12];
  #pragma unroll
  for (int i = 0; i < 8; ++i) f[i] = b2f(v0[i]);
  #pragma unroll
  for (int i = 0; i < 4; ++i) f[8 + i] = b2f(v1[i]);
  float s = 0.f, q = 0.f;
  #pragma unroll
  for (int i = 0; i < 12; ++i) { s += f[i]; q += f[i] * f[i]; }
  #pragma unroll
  for (int off = 1; off < 64; off <<= 1) { s += __shfl_xor(s, off); q += __shfl_xor(q, off); }
  const float mean = s * (1.f / 768.f);
  const float var = q * (1.f / 768.f) - mean * mean;
  const float r = rsqrtf(var + 1e-6f);
  float4 s0 = *(const float4*)(sc + l * 8);
  float4 s1 = *(const float4*)(sc + l * 8 + 4);
  float4 s2 = *(const float4*)(sc + 512 + l * 4);
  float4 b0 = *(const float4*)(bi + l * 8);
  float4 b1 = *(const float4*)(bi + l * 8 + 4);
  float4 b2 = *(const float4*)(bi + 512 + l * 4);
  float g[12];
  g[0] = (f[0]-mean)*r*s0.x + b0.x;  g[1] = (f[1]-mean)*r*s0.y + b0.y;
  g[2] = (f[2]-mean)*r*s0.z + b0.z;  g[3] = (f[3]-mean)*r*s0.w + b0.w;
  g[4] = (f[4]-mean)*r*s1.x + b1.x;  g[5] = (f[5]-mean)*r*s1.y + b1.y;
  g[6] = (f[6]-mean)*r*s1.z + b1.z;  g[7] = (f[7]-mean)*r*s1.w + b1.w;
  g[8] = (f[8]-mean)*r*s2.x + b2.x;  g[9] = (f[9]-mean)*r*s2.y + b2.y;
  g[10] = (f[10]-mean)*r*s2.z + b2.z; g[11] = (f[11]-mean)*r*s2.w + b2.w;
  u16* yr = y + (size_t)tok * 768;
  u32x4 o;
  o[0] = cvtpk(g[0], g[1]); o[1] = cvtpk(g[2], g[3]);
  o[2] = cvtpk(g[4], g[5]); o[3] = cvtpk(g[6], g[7]);
  *(u32x4*)(yr + l * 8) = o;
  u32x2 o2; o2[0] = cvtpk(g[8], g[9]); o2[1] = cvtpk(g[10], g[11]);
  *(u32x2*)(yr + 512 + l * 4) = o2;
}

// ---------------- bf16 GEMM 128x128, BK=64, 4 waves, counted-vmcnt ----------
// C[M,N] = A[M,K] @ Bt[N,K]^T (+fused epilogue). All outputs bf16.
enum { EPI_BF16 = 0, EPI_RESID = 1, EPI_GELU = 2, EPI_RELU = 3 };

__global__ __launch_bounds__(256, 2) void gemm128(
    const u16* __restrict__ A, const u16* __restrict__ Bt,
    const float* __restrict__ bias, const u16* __restrict__ residB,
    u16* __restrict__ outB, int N, int K, int nxb, int epi) {
  __shared__ u16 smem[32768];   // As[2][8192] @ 0, Bs[2][8192] @ 16384
  const int tid = threadIdx.x;
  const int w = tid >> 6, l = tid & 63;

  const int nwg = gridDim.x;
  const int flat = blockIdx.x;
  const int wg = (flat & 7) * (nwg >> 3) + (flat >> 3);
  const int bx = wg % nxb, by = wg / nxb;
  const int m0 = by << 7, n0 = bx << 7;

  const int wr = (w >> 1) << 6, wc = (w & 1) << 6;
  const int cl = l & 15, g = l >> 4;
  f32x4 acc[4][4] = {};

  const int lrow = l >> 3;
  const int scol = ((l & 7) ^ lrow) << 3;
  const u16* agp = A  + (size_t)(m0 + (w << 5) + lrow) * K + scol;
  const u16* bgp = Bt + (size_t)(n0 + (w << 5) + lrow) * K + scol;
  const int ldso = w << 11;
  const int nkt = K >> 6;

  #pragma unroll
  for (int q = 0; q < 4; ++q) {
    gload16(agp + (size_t)(q * 8) * K, &smem[ldso + (q << 9)]);
    gload16(bgp + (size_t)(q * 8) * K, &smem[16384 + ldso + (q << 9)]);
  }

  const int sw = cl & 7;
  for (int kt = 0; kt < nkt; ++kt) {
    const int cur = kt & 1;
    if (kt + 1 < nkt) {
      const size_t koff = (size_t)(kt + 1) << 6;
      const int nb = (cur ^ 1) << 13;
      #pragma unroll
      for (int q = 0; q < 4; ++q) {
        gload16(agp + koff + (size_t)(q * 8) * K, &smem[nb + ldso + (q << 9)]);
        gload16(bgp + koff + (size_t)(q * 8) * K, &smem[16384 + nb + ldso + (q << 9)]);
      }
      asm volatile("s_waitcnt vmcnt(8)" ::: "memory");
    } else {
      asm volatile("s_waitcnt vmcnt(0)" ::: "memory");
    }
    __builtin_amdgcn_s_barrier();
    __builtin_amdgcn_sched_barrier(0);
    const u16* Ab = &smem[cur << 13];
    const u16* Bb = &smem[16384 + (cur << 13)];
    #pragma unroll
    for (int ks = 0; ks < 2; ++ks) {
      bf16x8 af[4], bfr[4];
      const int ps = (((ks << 2) | g) ^ sw) << 3;
      #pragma unroll
      for (int mt = 0; mt < 4; ++mt)
        af[mt] = *(const bf16x8*)(Ab + ((wr + mt * 16 + cl) << 6) + ps);
      #pragma unroll
      for (int nt = 0; nt < 4; ++nt)
        bfr[nt] = *(const bf16x8*)(Bb + ((wc + nt * 16 + cl) << 6) + ps);
      #pragma unroll
      for (int mt = 0; mt < 4; ++mt)
        #pragma unroll
        for (int nt = 0; nt < 4; ++nt)
          acc[mt][nt] = __builtin_amdgcn_mfma_f32_16x16x32_bf16(af[mt], bfr[nt], acc[mt][nt], 0, 0, 0);
    }
    asm volatile("s_waitcnt lgkmcnt(0)" ::: "memory");
    __builtin_amdgcn_s_barrier();
  }

  // epilogue: per-wave LDS transpose -> coalesced bf16 stores
  float* scr = (float*)smem + w * 1056;
  const int rg = g << 2;
  const int er = l >> 3;
  const int ec0 = (l & 7) << 3;
  #pragma unroll
  for (int mt = 0; mt < 4; ++mt) {
    #pragma unroll
    for (int nt = 0; nt < 4; ++nt)
      #pragma unroll
      for (int j = 0; j < 4; ++j)
        scr[(rg + j) * 66 + nt * 16 + cl] = acc[mt][nt][j];
    #pragma unroll
    for (int t = 0; t < 2; ++t) {
      const int r = (t << 3) + er;
      const int grow = m0 + wr + mt * 16 + r;
      const int gcol = n0 + wc + ec0;
      float v[8];
      #pragma unroll
      for (int u = 0; u < 8; ++u) v[u] = scr[r * 66 + ec0 + u];
      if (bias) {
        #pragma unroll
        for (int u = 0; u < 8; ++u) v[u] += bias[gcol + u];
      }
      if (epi == EPI_RESID) {
        u16x8 rv = *(const u16x8*)(residB + (size_t)grow * N + gcol);
        #pragma unroll
        for (int u = 0; u < 8; ++u) v[u] += b2f(rv[u]);
      } else if (epi == EPI_GELU) {
        #pragma unroll
        for (int u = 0; u < 8; ++u) {
          const float x = v[u];
          const float e = __expf(-(1.5957691216f * x + 0.0713548163f * x * x * x));
          v[u] = x / (1.f + e);
        }
      } else if (epi == EPI_RELU) {
        #pragma unroll
        for (int u = 0; u < 8; ++u) v[u] = fmaxf(v[u], 0.f);
      }
      u32x4 ov;
      ov[0] = cvtpk(v[0], v[1]); ov[1] = cvtpk(v[2], v[3]);
      ov[2] = cvtpk(v[4], v[5]); ov[3] = cvtpk(v[6], v[7]);
      u32x4* op = (u32x4*)(outB + (size_t)grow * N + gcol);
      if (epi == EPI_BF16 || epi == EPI_GELU)
        __builtin_nontemporal_store(ov, op);   // streaming output
      else
        *op = ov;
    }
  }
}

// ---------------- flash attention (causal + ALiBi), XCD-chunked, balanced ----
__global__ __launch_bounds__(512, 2) void attn_kernel(const u16* __restrict__ qkv,
                                                      u16* __restrict__ o) {
  __shared__ u16 Ksm[2][4096];       // [64][64] linear, XOR-swizzled slots
  __shared__ u16 Vt[2][64][68];      // [dh][key], pad 4
  __shared__ u16 P[8][16][72];       // per-wave P strip [q][key]
  const int flat = blockIdx.x;
  const int b = flat & 7;
  const int rr = flat >> 3;
  const int h = rr >> 3;
  const int j = rr & 7;
  const int tid = threadIdx.x;
  const int w = tid >> 6, l = tid & 63;
  const int cl = l & 15, lg = l >> 4;
  const int qtile = (w < 4) ? j : 15 - j;
  const int q0 = qtile * 64 + (w & 3) * 16;
  const int rowg = q0 + cl;
  const float log2e = 1.44269504f;
  const float scale2 = 0.125f * log2e;
  const float slope = (h < 8) ? exp2f(-(float)(h + 1)) : exp2f(-0.5f - (float)(h - 8));
  const float slope2 = slope * log2e;
  const size_t rs_ = 2304;
  const size_t bbase = (size_t)b * 1024 * rs_;

  const u16* qp = qkv + bbase + (size_t)rowg * rs_ + h * 64 + lg * 8;
  bf16x8 qa0 = *(const bf16x8*)qp;
  bf16x8 qa1 = *(const bf16x8*)(qp + 32);

  float m_r = -1e30f, l_r = 0.f;
  f32x4 oacc[4];
  #pragma unroll
  for (int d = 0; d < 4; ++d) oacc[d] = (f32x4){0.f, 0.f, 0.f, 0.f};

  const u16* ksrc = qkv + bbase + (size_t)(tid >> 3) * rs_ + 768 + h * 64 +
                    (((tid & 7) ^ ((tid >> 3) & 7)) << 3);
  const int vd0 = w << 3;
  const u16* vbase = qkv + bbase + (size_t)l * rs_ + 1536 + h * 64 + vd0;

  const int nkv = 16 - j;
  gload16(ksrc, &Ksm[0][w << 9]);
  u16x8 vreg = *(const u16x8*)vbase;
  __syncthreads();

  const int sw = cl & 7;
  const int ps0 = (lg ^ sw) << 3;
  const int ps1 = ps0 ^ 32;

  for (int kv = 0; kv < nkv; ++kv) {
    const int buf = kv & 1;
    #pragma unroll
    for (int i = 0; i < 8; ++i) Vt[buf][vd0 + i][l] = vreg[i];
    u16x8 vnext = vreg;
    if (kv + 1 < nkv) {
      gload16(ksrc + (size_t)(kv + 1) * 64 * rs_, &Ksm[buf ^ 1][w << 9]);
      vnext = *(const u16x8*)(vbase + (size_t)(kv + 1) * 64 * rs_);
    }

    const bool active = (kv <= qtile);
    bf16x8 pa0, pa1;
    if (active) {
      const u16* Kb = &Ksm[buf][0];
      f32x4 pp[4];
      float pm = -3.0e38f;
      __builtin_amdgcn_s_setprio(1);
      #pragma unroll
      for (int nt = 0; nt < 4; ++nt) {
        const int row = nt * 16 + cl;
        bf16x8 bk0 = *(const bf16x8*)(Kb + (row << 6) + ps0);
        bf16x8 bk1 = *(const bf16x8*)(Kb + (row << 6) + ps1);
        f32x4 s = (f32x4){0.f, 0.f, 0.f, 0.f};
        s = __builtin_amdgcn_mfma_f32_16x16x32_bf16(bk0, qa0, s, 0, 0, 0);
        s = __builtin_amdgcn_mfma_f32_16x16x32_bf16(bk1, qa1, s, 0, 0, 0);
        const int kb = kv * 64 + nt * 16 + (lg << 2);
        #pragma unroll
        for (int jj = 0; jj < 4; ++jj) {
          const int colg = kb + jj;
          float v = s[jj] * scale2 + slope2 * (float)colg;
          pp[nt][jj] = (colg <= rowg) ? v : -3.0e38f;
        }
        pm = fmaxf(pm, fmaxf(fmaxf(pp[nt][0], pp[nt][1]),
                             fmaxf(pp[nt][2], pp[nt][3])));
      }
      __builtin_amdgcn_s_setprio(0);
      pm = fmaxf(pm, __shfl_xor(pm, 16));
      pm = fmaxf(pm, __shfl_xor(pm, 32));
      // T13 defer-max: skip rescale while new max within 2^11.54 of running max
      if (!__all(pm <= m_r + 11.54f)) {
        const float mnew = fmaxf(m_r, pm);
        const float al = fexp2(m_r - mnew);
        m_r = mnew;
        l_r *= al;
        float a4[4];
        #pragma unroll
        for (int jj = 0; jj < 4; ++jj) a4[jj] = __shfl(al, (lg << 2) + jj);
        #pragma unroll
        for (int d = 0; d < 4; ++d)
          #pragma unroll
          for (int jj = 0; jj < 4; ++jj) oacc[d][jj] *= a4[jj];
      }
      float rs = 0.f;
      #pragma unroll
      for (int nt = 0; nt < 4; ++nt) {
        #pragma unroll
        for (int jj = 0; jj < 4; ++jj) {
          float p = fexp2(pp[nt][jj] - m_r);
          pp[nt][jj] = p;
          rs += p;
        }
      }
      rs += __shfl_xor(rs, 16);
      rs += __shfl_xor(rs, 32);
      l_r += rs;
      #pragma unroll
      for (int nt = 0; nt < 4; ++nt) {
        u32x2 pr;
        pr[0] = cvtpk(pp[nt][0], pp[nt][1]);
        pr[1] = cvtpk(pp[nt][2], pp[nt][3]);
        *(u32x2*)&P[w][cl][nt * 16 + (lg << 2)] = pr;
      }
      pa0 = *(const bf16x8*)&P[w][cl][lg * 8];
      pa1 = *(const bf16x8*)&P[w][cl][32 + lg * 8];
    }

    __syncthreads();

    if (active) {
      __builtin_amdgcn_s_setprio(1);
      #pragma unroll
      for (int d = 0; d < 4; ++d) {
        bf16x8 bv0 = *(const bf16x8*)&Vt[buf][d * 16 + cl][lg * 8];
        bf16x8 bv1 = *(const bf16x8*)&Vt[buf][d * 16 + cl][32 + lg * 8];
        oacc[d] = __builtin_amdgcn_mfma_f32_16x16x32_bf16(pa0, bv0, oacc[d], 0, 0, 0);
        oacc[d] = __builtin_amdgcn_mfma_f32_16x16x32_bf16(pa1, bv1, oacc[d], 0, 0, 0);
      }
      __builtin_amdgcn_s_setprio(0);
    }
    vreg = vnext;
  }

  const float linv = 1.f / l_r;
  float i4[4];
  #pragma unroll
  for (int jj = 0; jj < 4; ++jj) i4[jj] = __shfl(linv, (lg << 2) + jj);
  u16* op = o + ((size_t)b * 1024 + q0) * 768 + h * 64;
  #pragma unroll
  for (int d = 0; d < 4; ++d)
    #pragma unroll
    for (int jj = 0; jj < 4; ++jj)
      op[(size_t)((lg << 2) + jj) * 768 + d * 16 + cl] = f2bf(oacc[d][jj] * i4[jj]);
}

// ---------------- action head: out[M,7] = act[M,768] @ w[768,7] --------------
__global__ __launch_bounds__(256) void head2_kernel(const u16* __restrict__ act,
                                                    const float* __restrict__ w,
                                                    float* __restrict__ out, int Mtok) {
  const int bid = blockIdx.x;
  const int tok = ((bid & 7) << 10) + ((bid >> 3) << 2) + (threadIdx.x >> 6);
  const int l = threadIdx.x & 63;
  if (tok >= Mtok) return;
  float s[7] = {0.f, 0.f, 0.f, 0.f, 0.f, 0.f, 0.f};
  const u16* ar = act + (size_t)tok * 768;
  #pragma unroll
  for (int i = 0; i < 12; ++i) {
    const int k = l + i * 64;
    const float a = b2f(ar[k]);
    #pragma unroll
    for (int j = 0; j < 7; ++j) s[j] += a * w[k * 7 + j];
  }
  #pragma unroll
  for (int off = 32; off; off >>= 1)
    #pragma unroll
    for (int j = 0; j < 7; ++j) s[j] += __shfl_down(s[j], off);
  if (l == 0) {
    #pragma unroll
    for (int j = 0; j < 7; ++j) out[(size_t)tok * 7 + j] = s[j];
  }
}

// ---------------- orchestration ---------------------------------------------
extern "C" void kernel_launch(void* const* d_in, const int* in_sizes, int n_in,
                              void* d_out, int out_size, void* d_ws, size_t ws_size,
                              hipStream_t stream) {
  const float* x_in = (const float*)d_in[0];
  const float* ln1s = (const float*)d_in[1];
  const float* ln1b = (const float*)d_in[2];
  const float* wqkv = (const float*)d_in[3];
  const float* bqkv = (const float*)d_in[4];
  const float* wo   = (const float*)d_in[5];
  const float* bo   = (const float*)d_in[6];
  const float* ln2s = (const float*)d_in[7];
  const float* ln2b = (const float*)d_in[8];
  const float* w1   = (const float*)d_in[9];
  const float* w2   = (const float*)d_in[10];
  const float* lnfs = (const float*)d_in[11];
  const float* lnfb = (const float*)d_in[12];
  const float* hw1  = (const float*)d_in[13];
  const float* hb1  = (const float*)d_in[14];
  const float* hw2  = (const float*)d_in[15];
  float* out = (float*)d_out;

  const int Mtok = 8192, E = 768, E3 = 2304, F = 3072, DEPTH = 6;

  char* ws = (char*)d_ws;
  size_t off = 0;
  auto alloc = [&](size_t bytes) -> char* {
    char* p = ws + off; off += (bytes + 255) & ~(size_t)255; return p;
  };
  u16*  wqkvt = (u16*)alloc((size_t)DEPTH * E3 * E * 2);
  u16*  wot   = (u16*)alloc((size_t)DEPTH * E * E * 2);
  u16*  w1t   = (u16*)alloc((size_t)DEPTH * F * E * 2);
  u16*  w2t   = (u16*)alloc((size_t)DEPTH * E * F * 2);
  u16*  hw1t  = (u16*)alloc((size_t)E * E * 2);
  u16*  xb    = (u16*)alloc((size_t)Mtok * E * 2);   // bf16 residual stream
  u16*  yb    = (u16*)alloc((size_t)Mtok * E * 2);
  u16*  big   = (u16*)alloc((size_t)Mtok * F * 2);
  (void)ws_size; (void)in_sizes; (void)n_in; (void)out_size;

  TArgs ta; int nm = 0; int t0 = 0;
  auto add = [&](const float* s, u16* d, int K, int N) {
    ta.m[nm].src = s; ta.m[nm].dst = d; ta.m[nm].K = K; ta.m[nm].N = N; ta.m[nm].t0 = t0;
    t0 += (N / 64) * (K / 128); ++nm;
  };
  for (int i = 0; i < DEPTH; ++i) add(wqkv + (size_t)i * E * E3, wqkvt + (size_t)i * E3 * E, E, E3);
  for (int i = 0; i < DEPTH; ++i) add(wo + (size_t)i * E * E, wot + (size_t)i * E * E, E, E);
  for (int i = 0; i < DEPTH; ++i) add(w1 + (size_t)i * E * F, w1t + (size_t)i * F * E, E, F);
  for (int i = 0; i < DEPTH; ++i) add(w2 + (size_t)i * F * E, w2t + (size_t)i * E * F, F, E);
  add(hw1, hw1t, E, E);
  ta.nmat = nm;
  transpose_all<<<t0, 256, 0, stream>>>(ta);

  // x_in fp32 -> bf16 residual stream
  f2b_kernel<<<(Mtok * E / 8 + 255) / 256, 256, 0, stream>>>(
      (const f32x4*)x_in, (u32x4*)xb, Mtok * E / 8);

  u16* qkvb = big;
  for (int i = 0; i < DEPTH; ++i) {
    ln_kernel<<<Mtok / 4, 256, 0, stream>>>(xb, ln1s + i * E, ln1b + i * E, yb, Mtok);
    gemm128<<<18 * 64, 256, 0, stream>>>(yb, wqkvt + (size_t)i * E3 * E, bqkv + (size_t)i * E3,
                                         nullptr, qkvb, E3, E, 18, EPI_BF16);
    attn_kernel<<<768, 512, 0, stream>>>(qkvb, yb);
    gemm128<<<6 * 64, 256, 0, stream>>>(yb, wot + (size_t)i * E * E, bo + (size_t)i * E,
                                        xb, xb, E, E, 6, EPI_RESID);
    ln_kernel<<<Mtok / 4, 256, 0, stream>>>(xb, ln2s + i * E, ln2b + i * E, yb, Mtok);
    gemm128<<<24 * 64, 256, 0, stream>>>(yb, w1t + (size_t)i * F * E, nullptr,
                                         nullptr, big, F, E, 24, EPI_GELU);
    gemm128<<<6 * 64, 256, 0, stream>>>(big, w2t + (size_t)i * E * F, nullptr,
                                        xb, xb, E, F, 6, EPI_RESID);
  }
  ln_kernel<<<Mtok / 4, 256, 0, stream>>>(xb, lnfs, lnfb, yb, Mtok);
  gemm128<<<6 * 64, 256, 0, stream>>>(yb, hw1t, hb1, nullptr, big,
                                      E, E, 6, EPI_RELU);
  head2_kernel<<<Mtok / 4, 256, 0, stream>>>(big, hw2, out, Mtok);
}

// Round 17
// 1415.631 us; speedup vs baseline: 1.0410x; 1.0410x over previous
//
#include <hip/hip_runtime.h>
#include <hip/hip_bf16.h>
#include <cstdint>

#define DEV __device__ __forceinline__

typedef __bf16 bf16x8 __attribute__((ext_vector_type(8)));
typedef float f32x4 __attribute__((ext_vector_type(4)));
typedef unsigned short u16;
typedef u16 u16x8 __attribute__((ext_vector_type(8)));
typedef u16 u16x4 __attribute__((ext_vector_type(4)));
typedef uint32_t u32x2 __attribute__((ext_vector_type(2)));
typedef uint32_t u32x4 __attribute__((ext_vector_type(4)));

DEV u16 f2bf(float f) {
  union { float f; uint32_t u; } a; a.f = f;
  uint32_t u = a.u + 0x7fffu + ((a.u >> 16) & 1u);
  return (u16)(u >> 16);
}
DEV float b2f(u16 v) {
  union { uint32_t u; float f; } a; a.u = ((uint32_t)v) << 16;
  return a.f;
}

DEV float fexp2(float x) {
#if __has_builtin(__builtin_amdgcn_exp2f)
  return __builtin_amdgcn_exp2f(x);
#else
  return __expf(x * 0.69314718056f);
#endif
}

DEV uint32_t cvtpk(float lo, float hi) {
  uint32_t r;
  asm("v_cvt_pk_bf16_f32 %0, %1, %2" : "=v"(r) : "v"(lo), "v"(hi));
  return r;
}

DEV void gload16(const void* g, void* lds) {
  __builtin_amdgcn_global_load_lds((__attribute__((address_space(1))) void*)g,
                                   (__attribute__((address_space(3))) void*)lds,
                                   16, 0, 0);
}

// ---------------- weight convert + transpose: dst[n][k] = bf16(src[k][n]) ----
// Tiles of 64 output rows (n) x 128 k -> 256B/output-row (full HBM sector).
struct TMat { const float* src; u16* dst; int K; int N; int t0; };
struct TArgs { TMat m[26]; int nmat; };

__global__ __launch_bounds__(256) void transpose_all(TArgs args) {
  __shared__ float tile[128][65];
  const int bid = blockIdx.x;
  int i = 0;
  #pragma unroll 1
  for (int t = 1; t < args.nmat; ++t) if (bid >= args.m[t].t0) i = t;
  const TMat mm = args.m[i];
  const int tid = threadIdx.x;
  const int tix = bid - mm.t0;
  const int ntx = mm.N >> 6;
  const int n0 = (tix % ntx) << 6, k0 = (tix / ntx) << 7;
  const int lr = tid >> 4, lc4 = (tid & 15) << 2;
  #pragma unroll
  for (int p = 0; p < 8; ++p) {
    const int r = lr + (p << 4);
    f32x4 v = __builtin_nontemporal_load(
        (const f32x4*)(mm.src + (size_t)(k0 + r) * mm.N + n0 + lc4));
    *(f32x4*)&tile[r][lc4] = v;
  }
  __syncthreads();
  const int ks8 = (tid & 15) << 3;
  #pragma unroll
  for (int p = 0; p < 4; ++p) {
    const int n = (tid >> 4) + (p << 4);
    float v[8];
    #pragma unroll
    for (int u = 0; u < 8; ++u) v[u] = tile[ks8 + u][n];
    u32x4 o;
    o[0] = cvtpk(v[0], v[1]); o[1] = cvtpk(v[2], v[3]);
    o[2] = cvtpk(v[4], v[5]); o[3] = cvtpk(v[6], v[7]);
    __builtin_nontemporal_store(
        o, (u32x4*)(mm.dst + (size_t)(n0 + n) * mm.K + k0 + ks8));
  }
}

// ---------------- fp32 -> bf16 convert (x_in -> xb) --------------------------
__global__ __launch_bounds__(256) void f2b_kernel(const f32x4* __restrict__ in,
                                                  u32x4* __restrict__ out, int n8) {
  const int i = blockIdx.x * 256 + threadIdx.x;
  if (i >= n8) return;
  f32x4 a = __builtin_nontemporal_load(in + 2 * i);
  f32x4 b = __builtin_nontemporal_load(in + 2 * i + 1);
  u32x4 o;
  o[0] = cvtpk(a[0], a[1]); o[1] = cvtpk(a[2], a[3]);
  o[2] = cvtpk(b[0], b[1]); o[3] = cvtpk(b[2], b[3]);
  __builtin_nontemporal_store(o, out + i);
}

// ---------------- LayerNorm: bf16 in -> bf16 out, XCD-aligned tokens --------
__global__ __launch_bounds__(256) void ln_kernel(const u16* __restrict__ x,
                                                 const float* __restrict__ sc,
                                                 const float* __restrict__ bi,
                                                 u16* __restrict__ y, int Mtok) {
  const int bid = blockIdx.x;
  const int tok = ((bid & 7) << 10) + ((bid >> 3) << 2) + (threadIdx.x >> 6);
  const int l = threadIdx.x & 63;
  if (tok >= Mtok) return;
  const u16* row = x + (size_t)tok * 768;
  u16x8 v0 = *(const u16x8*)(row + l * 8);
  u16x4 v1 = *(const u16x4*)(row + 512 + l * 4);
  float f[12];
  #pragma unroll
  for (int i = 0; i < 8; ++i) f[i] = b2f(v0[i]);
  #pragma unroll
  for (int i = 0; i < 4; ++i) f[8 + i] = b2f(v1[i]);
  float s = 0.f, q = 0.f;
  #pragma unroll
  for (int i = 0; i < 12; ++i) { s += f[i]; q += f[i] * f[i]; }
  #pragma unroll
  for (int off = 1; off < 64; off <<= 1) { s += __shfl_xor(s, off); q += __shfl_xor(q, off); }
  const float mean = s * (1.f / 768.f);
  const float var = q * (1.f / 768.f) - mean * mean;
  const float r = rsqrtf(var + 1e-6f);
  float4 s0 = *(const float4*)(sc + l * 8);
  float4 s1 = *(const float4*)(sc + l * 8 + 4);
  float4 s2 = *(const float4*)(sc + 512 + l * 4);
  float4 b0 = *(const float4*)(bi + l * 8);
  float4 b1 = *(const float4*)(bi + l * 8 + 4);
  float4 b2 = *(const float4*)(bi + 512 + l * 4);
  float g[12];
  g[0] = (f[0]-mean)*r*s0.x + b0.x;  g[1] = (f[1]-mean)*r*s0.y + b0.y;
  g[2] = (f[2]-mean)*r*s0.z + b0.z;  g[3] = (f[3]-mean)*r*s0.w + b0.w;
  g[4] = (f[4]-mean)*r*s1.x + b1.x;  g[5] = (f[5]-mean)*r*s1.y + b1.y;
  g[6] = (f[6]-mean)*r*s1.z + b1.z;  g[7] = (f[7]-mean)*r*s1.w + b1.w;
  g[8] = (f[8]-mean)*r*s2.x + b2.x;  g[9] = (f[9]-mean)*r*s2.y + b2.y;
  g[10] = (f[10]-mean)*r*s2.z + b2.z; g[11] = (f[11]-mean)*r*s2.w + b2.w;
  u16* yr = y + (size_t)tok * 768;
  u32x4 o;
  o[0] = cvtpk(g[0], g[1]); o[1] = cvtpk(g[2], g[3]);
  o[2] = cvtpk(g[4], g[5]); o[3] = cvtpk(g[6], g[7]);
  *(u32x4*)(yr + l * 8) = o;
  u32x2 o2; o2[0] = cvtpk(g[8], g[9]); o2[1] = cvtpk(g[10], g[11]);
  *(u32x2*)(yr + 512 + l * 4) = o2;
}

// ---------------- bf16 GEMM 128x128, BK=64, 8 waves, counted-vmcnt ----------
// Wave tile 64x32 (acc 4x2). 16 waves/CU (2 blocks) for cross-wave overlap.
enum { EPI_BF16 = 0, EPI_RESID = 1, EPI_GELU = 2, EPI_RELU = 3 };

__global__ __launch_bounds__(512, 4) void gemm128(
    const u16* __restrict__ A, const u16* __restrict__ Bt,
    const float* __restrict__ bias, const u16* __restrict__ residB,
    u16* __restrict__ outB, int N, int K, int nxb, int epi) {
  __shared__ u16 smem[32768];   // As[2][8192] @ 0, Bs[2][8192] @ 16384
  const int tid = threadIdx.x;
  const int w = tid >> 6, l = tid & 63;

  const int nwg = gridDim.x;
  const int flat = blockIdx.x;
  const int wg = (flat & 7) * (nwg >> 3) + (flat >> 3);
  const int bx = wg % nxb, by = wg / nxb;
  const int m0 = by << 7, n0 = bx << 7;

  const int wr = (w >> 2) << 6;          // 0 / 64
  const int wc = (w & 3) << 5;           // 0,32,64,96
  const int cl = l & 15, g = l >> 4;
  f32x4 acc[4][2] = {};

  // staging: wave w stages A rows [w*16,w*16+16) and B rows same; 2 gloads each
  const int lrow = l >> 3;
  const int scol = ((l & 7) ^ lrow) << 3;
  const u16* agp = A  + (size_t)(m0 + (w << 4) + lrow) * K + scol;
  const u16* bgp = Bt + (size_t)(n0 + (w << 4) + lrow) * K + scol;
  const int ldso = w << 10;              // 16 rows x 64 elems
  const int nkt = K >> 6;

  #pragma unroll
  for (int q = 0; q < 2; ++q) {
    gload16(agp + (size_t)(q * 8) * K, &smem[ldso + (q << 9)]);
    gload16(bgp + (size_t)(q * 8) * K, &smem[16384 + ldso + (q << 9)]);
  }

  const int sw = cl & 7;
  for (int kt = 0; kt < nkt; ++kt) {
    const int cur = kt & 1;
    if (kt + 1 < nkt) {
      const size_t koff = (size_t)(kt + 1) << 6;
      const int nb = (cur ^ 1) << 13;
      #pragma unroll
      for (int q = 0; q < 2; ++q) {
        gload16(agp + koff + (size_t)(q * 8) * K, &smem[nb + ldso + (q << 9)]);
        gload16(bgp + koff + (size_t)(q * 8) * K, &smem[16384 + nb + ldso + (q << 9)]);
      }
      asm volatile("s_waitcnt vmcnt(4)" ::: "memory");
    } else {
      asm volatile("s_waitcnt vmcnt(0)" ::: "memory");
    }
    __builtin_amdgcn_s_barrier();
    __builtin_amdgcn_sched_barrier(0);
    const u16* Ab = &smem[cur << 13];
    const u16* Bb = &smem[16384 + (cur << 13)];
    #pragma unroll
    for (int ks = 0; ks < 2; ++ks) {
      bf16x8 af[4], bfr[2];
      const int ps = (((ks << 2) | g) ^ sw) << 3;
      #pragma unroll
      for (int mt = 0; mt < 4; ++mt)
        af[mt] = *(const bf16x8*)(Ab + ((wr + mt * 16 + cl) << 6) + ps);
      #pragma unroll
      for (int nt = 0; nt < 2; ++nt)
        bfr[nt] = *(const bf16x8*)(Bb + ((wc + nt * 16 + cl) << 6) + ps);
      #pragma unroll
      for (int mt = 0; mt < 4; ++mt)
        #pragma unroll
        for (int nt = 0; nt < 2; ++nt)
          acc[mt][nt] = __builtin_amdgcn_mfma_f32_16x16x32_bf16(af[mt], bfr[nt], acc[mt][nt], 0, 0, 0);
    }
    asm volatile("s_waitcnt lgkmcnt(0)" ::: "memory");
    __builtin_amdgcn_s_barrier();
  }

  // epilogue: per-wave LDS transpose (16x34 fp32) -> coalesced bf16 stores
  float* scr = (float*)smem + w * 544;
  const int rg = g << 2;
  const int er = l >> 2;                 // 0..15
  const int ec0 = (l & 3) << 3;          // 0,8,16,24
  #pragma unroll
  for (int mt = 0; mt < 4; ++mt) {
    #pragma unroll
    for (int nt = 0; nt < 2; ++nt)
      #pragma unroll
      for (int j = 0; j < 4; ++j)
        scr[(rg + j) * 34 + nt * 16 + cl] = acc[mt][nt][j];
    const int grow = m0 + wr + mt * 16 + er;
    const int gcol = n0 + wc + ec0;
    float v[8];
    #pragma unroll
    for (int u = 0; u < 8; ++u) v[u] = scr[er * 34 + ec0 + u];
    if (bias) {
      #pragma unroll
      for (int u = 0; u < 8; ++u) v[u] += bias[gcol + u];
    }
    if (epi == EPI_RESID) {
      u16x8 rv = *(const u16x8*)(residB + (size_t)grow * N + gcol);
      #pragma unroll
      for (int u = 0; u < 8; ++u) v[u] += b2f(rv[u]);
    } else if (epi == EPI_GELU) {
      #pragma unroll
      for (int u = 0; u < 8; ++u) {
        const float x = v[u];
        const float e = __expf(-(1.5957691216f * x + 0.0713548163f * x * x * x));
        v[u] = x / (1.f + e);
      }
    } else if (epi == EPI_RELU) {
      #pragma unroll
      for (int u = 0; u < 8; ++u) v[u] = fmaxf(v[u], 0.f);
    }
    u32x4 ov;
    ov[0] = cvtpk(v[0], v[1]); ov[1] = cvtpk(v[2], v[3]);
    ov[2] = cvtpk(v[4], v[5]); ov[3] = cvtpk(v[6], v[7]);
    u32x4* op = (u32x4*)(outB + (size_t)grow * N + gcol);
    if (epi == EPI_BF16 || epi == EPI_GELU)
      __builtin_nontemporal_store(ov, op);
    else
      *op = ov;
  }
}

// ---------------- flash attention (causal + ALiBi), XCD-chunked, balanced ----
__global__ __launch_bounds__(512, 2) void attn_kernel(const u16* __restrict__ qkv,
                                                      u16* __restrict__ o) {
  __shared__ u16 Ksm[2][4096];
  __shared__ u16 Vt[2][64][68];
  __shared__ u16 P[8][16][72];
  const int flat = blockIdx.x;
  const int b = flat & 7;
  const int rr = flat >> 3;
  const int h = rr >> 3;
  const int j = rr & 7;
  const int tid = threadIdx.x;
  const int w = tid >> 6, l = tid & 63;
  const int cl = l & 15, lg = l >> 4;
  const int qtile = (w < 4) ? j : 15 - j;
  const int q0 = qtile * 64 + (w & 3) * 16;
  const int rowg = q0 + cl;
  const float log2e = 1.44269504f;
  const float scale2 = 0.125f * log2e;
  const float slope = (h < 8) ? exp2f(-(float)(h + 1)) : exp2f(-0.5f - (float)(h - 8));
  const float slope2 = slope * log2e;
  const size_t rs_ = 2304;
  const size_t bbase = (size_t)b * 1024 * rs_;

  const u16* qp = qkv + bbase + (size_t)rowg * rs_ + h * 64 + lg * 8;
  bf16x8 qa0 = *(const bf16x8*)qp;
  bf16x8 qa1 = *(const bf16x8*)(qp + 32);

  float m_r = -1e30f, l_r = 0.f;
  f32x4 oacc[4];
  #pragma unroll
  for (int d = 0; d < 4; ++d) oacc[d] = (f32x4){0.f, 0.f, 0.f, 0.f};

  const u16* ksrc = qkv + bbase + (size_t)(tid >> 3) * rs_ + 768 + h * 64 +
                    (((tid & 7) ^ ((tid >> 3) & 7)) << 3);
  const int vd0 = w << 3;
  const u16* vbase = qkv + bbase + (size_t)l * rs_ + 1536 + h * 64 + vd0;

  const int nkv = 16 - j;
  gload16(ksrc, &Ksm[0][w << 9]);
  u16x8 vreg = *(const u16x8*)vbase;
  __syncthreads();

  const int sw = cl & 7;
  const int ps0 = (lg ^ sw) << 3;
  const int ps1 = ps0 ^ 32;

  for (int kv = 0; kv < nkv; ++kv) {
    const int buf = kv & 1;
    #pragma unroll
    for (int i = 0; i < 8; ++i) Vt[buf][vd0 + i][l] = vreg[i];
    u16x8 vnext = vreg;
    if (kv + 1 < nkv) {
      gload16(ksrc + (size_t)(kv + 1) * 64 * rs_, &Ksm[buf ^ 1][w << 9]);
      vnext = *(const u16x8*)(vbase + (size_t)(kv + 1) * 64 * rs_);
    }

    const bool active = (kv <= qtile);
    bf16x8 pa0, pa1;
    if (active) {
      const u16* Kb = &Ksm[buf][0];
      f32x4 pp[4];
      float pm = -3.0e38f;
      __builtin_amdgcn_s_setprio(1);
      #pragma unroll
      for (int nt = 0; nt < 4; ++nt) {
        const int row = nt * 16 + cl;
        bf16x8 bk0 = *(const bf16x8*)(Kb + (row << 6) + ps0);
        bf16x8 bk1 = *(const bf16x8*)(Kb + (row << 6) + ps1);
        f32x4 s = (f32x4){0.f, 0.f, 0.f, 0.f};
        s = __builtin_amdgcn_mfma_f32_16x16x32_bf16(bk0, qa0, s, 0, 0, 0);
        s = __builtin_amdgcn_mfma_f32_16x16x32_bf16(bk1, qa1, s, 0, 0, 0);
        const int kb = kv * 64 + nt * 16 + (lg << 2);
        #pragma unroll
        for (int jj = 0; jj < 4; ++jj) {
          const int colg = kb + jj;
          float v = s[jj] * scale2 + slope2 * (float)colg;
          pp[nt][jj] = (colg <= rowg) ? v : -3.0e38f;
        }
        pm = fmaxf(pm, fmaxf(fmaxf(pp[nt][0], pp[nt][1]),
                             fmaxf(pp[nt][2], pp[nt][3])));
      }
      __builtin_amdgcn_s_setprio(0);
      pm = fmaxf(pm, __shfl_xor(pm, 16));
      pm = fmaxf(pm, __shfl_xor(pm, 32));
      if (!__all(pm <= m_r + 11.54f)) {
        const float mnew = fmaxf(m_r, pm);
        const float al = fexp2(m_r - mnew);
        m_r = mnew;
        l_r *= al;
        float a4[4];
        #pragma unroll
        for (int jj = 0; jj < 4; ++jj) a4[jj] = __shfl(al, (lg << 2) + jj);
        #pragma unroll
        for (int d = 0; d < 4; ++d)
          #pragma unroll
          for (int jj = 0; jj < 4; ++jj) oacc[d][jj] *= a4[jj];
      }
      float rs = 0.f;
      #pragma unroll
      for (int nt = 0; nt < 4; ++nt) {
        #pragma unroll
        for (int jj = 0; jj < 4; ++jj) {
          float p = fexp2(pp[nt][jj] - m_r);
          pp[nt][jj] = p;
          rs += p;
        }
      }
      rs += __shfl_xor(rs, 16);
      rs += __shfl_xor(rs, 32);
      l_r += rs;
      #pragma unroll
      for (int nt = 0; nt < 4; ++nt) {
        u32x2 pr;
        pr[0] = cvtpk(pp[nt][0], pp[nt][1]);
        pr[1] = cvtpk(pp[nt][2], pp[nt][3]);
        *(u32x2*)&P[w][cl][nt * 16 + (lg << 2)] = pr;
      }
      pa0 = *(const bf16x8*)&P[w][cl][lg * 8];
      pa1 = *(const bf16x8*)&P[w][cl][32 + lg * 8];
    }

    __syncthreads();

    if (active) {
      __builtin_amdgcn_s_setprio(1);
      #pragma unroll
      for (int d = 0; d < 4; ++d) {
        bf16x8 bv0 = *(const bf16x8*)&Vt[buf][d * 16 + cl][lg * 8];
        bf16x8 bv1 = *(const bf16x8*)&Vt[buf][d * 16 + cl][32 + lg * 8];
        oacc[d] = __builtin_amdgcn_mfma_f32_16x16x32_bf16(pa0, bv0, oacc[d], 0, 0, 0);
        oacc[d] = __builtin_amdgcn_mfma_f32_16x16x32_bf16(pa1, bv1, oacc[d], 0, 0, 0);
      }
      __builtin_amdgcn_s_setprio(0);
    }
    vreg = vnext;
  }

  const float linv = 1.f / l_r;
  float i4[4];
  #pragma unroll
  for (int jj = 0; jj < 4; ++jj) i4[jj] = __shfl(linv, (lg << 2) + jj);
  u16* op = o + ((size_t)b * 1024 + q0) * 768 + h * 64;
  #pragma unroll
  for (int d = 0; d < 4; ++d)
    #pragma unroll
    for (int jj = 0; jj < 4; ++jj)
      op[(size_t)((lg << 2) + jj) * 768 + d * 16 + cl] = f2bf(oacc[d][jj] * i4[jj]);
}

// ---------------- action head: out[M,7] = act[M,768] @ w[768,7] --------------
__global__ __launch_bounds__(256) void head2_kernel(const u16* __restrict__ act,
                                                    const float* __restrict__ w,
                                                    float* __restrict__ out, int Mtok) {
  const int bid = blockIdx.x;
  const int tok = ((bid & 7) << 10) + ((bid >> 3) << 2) + (threadIdx.x >> 6);
  const int l = threadIdx.x & 63;
  if (tok >= Mtok) return;
  float s[7] = {0.f, 0.f, 0.f, 0.f, 0.f, 0.f, 0.f};
  const u16* ar = act + (size_t)tok * 768;
  #pragma unroll
  for (int i = 0; i < 12; ++i) {
    const int k = l + i * 64;
    const float a = b2f(ar[k]);
    #pragma unroll
    for (int j = 0; j < 7; ++j) s[j] += a * w[k * 7 + j];
  }
  #pragma unroll
  for (int off = 32; off; off >>= 1)
    #pragma unroll
    for (int j = 0; j < 7; ++j) s[j] += __shfl_down(s[j], off);
  if (l == 0) {
    #pragma unroll
    for (int j = 0; j < 7; ++j) out[(size_t)tok * 7 + j] = s[j];
  }
}

// ---------------- orchestration ---------------------------------------------
extern "C" void kernel_launch(void* const* d_in, const int* in_sizes, int n_in,
                              void* d_out, int out_size, void* d_ws, size_t ws_size,
                              hipStream_t stream) {
  const float* x_in = (const float*)d_in[0];
  const float* ln1s = (const float*)d_in[1];
  const float* ln1b = (const float*)d_in[2];
  const float* wqkv = (const float*)d_in[3];
  const float* bqkv = (const float*)d_in[4];
  const float* wo   = (const float*)d_in[5];
  const float* bo   = (const float*)d_in[6];
  const float* ln2s = (const float*)d_in[7];
  const float* ln2b = (const float*)d_in[8];
  const float* w1   = (const float*)d_in[9];
  const float* w2   = (const float*)d_in[10];
  const float* lnfs = (const float*)d_in[11];
  const float* lnfb = (const float*)d_in[12];
  const float* hw1  = (const float*)d_in[13];
  const float* hb1  = (const float*)d_in[14];
  const float* hw2  = (const float*)d_in[15];
  float* out = (float*)d_out;

  const int Mtok = 8192, E = 768, E3 = 2304, F = 3072, DEPTH = 6;

  char* ws = (char*)d_ws;
  size_t off = 0;
  auto alloc = [&](size_t bytes) -> char* {
    char* p = ws + off; off += (bytes + 255) & ~(size_t)255; return p;
  };
  u16*  wqkvt = (u16*)alloc((size_t)DEPTH * E3 * E * 2);
  u16*  wot   = (u16*)alloc((size_t)DEPTH * E * E * 2);
  u16*  w1t   = (u16*)alloc((size_t)DEPTH * F * E * 2);
  u16*  w2t   = (u16*)alloc((size_t)DEPTH * E * F * 2);
  u16*  hw1t  = (u16*)alloc((size_t)E * E * 2);
  u16*  xb    = (u16*)alloc((size_t)Mtok * E * 2);
  u16*  yb    = (u16*)alloc((size_t)Mtok * E * 2);
  u16*  big   = (u16*)alloc((size_t)Mtok * F * 2);
  (void)ws_size; (void)in_sizes; (void)n_in; (void)out_size;

  TArgs ta; int nm = 0; int t0 = 0;
  auto add = [&](const float* s, u16* d, int K, int N) {
    ta.m[nm].src = s; ta.m[nm].dst = d; ta.m[nm].K = K; ta.m[nm].N = N; ta.m[nm].t0 = t0;
    t0 += (N / 64) * (K / 128); ++nm;
  };
  for (int i = 0; i < DEPTH; ++i) add(wqkv + (size_t)i * E * E3, wqkvt + (size_t)i * E3 * E, E, E3);
  for (int i = 0; i < DEPTH; ++i) add(wo + (size_t)i * E * E, wot + (size_t)i * E * E, E, E);
  for (int i = 0; i < DEPTH; ++i) add(w1 + (size_t)i * E * F, w1t + (size_t)i * F * E, E, F);
  for (int i = 0; i < DEPTH; ++i) add(w2 + (size_t)i * F * E, w2t + (size_t)i * E * F, F, E);
  add(hw1, hw1t, E, E);
  ta.nmat = nm;
  transpose_all<<<t0, 256, 0, stream>>>(ta);

  f2b_kernel<<<(Mtok * E / 8 + 255) / 256, 256, 0, stream>>>(
      (const f32x4*)x_in, (u32x4*)xb, Mtok * E / 8);

  u16* qkvb = big;
  for (int i = 0; i < DEPTH; ++i) {
    ln_kernel<<<Mtok / 4, 256, 0, stream>>>(xb, ln1s + i * E, ln1b + i * E, yb, Mtok);
    gemm128<<<18 * 64, 512, 0, stream>>>(yb, wqkvt + (size_t)i * E3 * E, bqkv + (size_t)i * E3,
                                         nullptr, qkvb, E3, E, 18, EPI_BF16);
    attn_kernel<<<768, 512, 0, stream>>>(qkvb, yb);
    gemm128<<<6 * 64, 512, 0, stream>>>(yb, wot + (size_t)i * E * E, bo + (size_t)i * E,
                                        xb, xb, E, E, 6, EPI_RESID);
    ln_kernel<<<Mtok / 4, 256, 0, stream>>>(xb, ln2s + i * E, ln2b + i * E, yb, Mtok);
    gemm128<<<24 * 64, 512, 0, stream>>>(yb, w1t + (size_t)i * F * E, nullptr,
                                         nullptr, big, F, E, 24, EPI_GELU);
    gemm128<<<6 * 64, 512, 0, stream>>>(big, w2t + (size_t)i * E * F, nullptr,
                                        xb, xb, E, F, 6, EPI_RESID);
  }
  ln_kernel<<<Mtok / 4, 256, 0, stream>>>(xb, lnfs, lnfb, yb, Mtok);
  gemm128<<<6 * 64, 512, 0, stream>>>(yb, hw1t, hb1, nullptr, big,
                                      E, E, 6, EPI_RELU);
  head2_kernel<<<Mtok / 4, 256, 0, stream>>>(big, hw2, out, Mtok);
}

// Round 18
// 1345.289 us; speedup vs baseline: 1.0954x; 1.0523x over previous
//
#include <hip/hip_runtime.h>
#include <hip/hip_bf16.h>
#include <cstdint>

#define DEV __device__ __forceinline__

typedef __bf16 bf16x8 __attribute__((ext_vector_type(8)));
typedef float f32x4 __attribute__((ext_vector_type(4)));
typedef unsigned short u16;
typedef u16 u16x8 __attribute__((ext_vector_type(8)));
typedef u16 u16x4 __attribute__((ext_vector_type(4)));
typedef uint32_t u32x2 __attribute__((ext_vector_type(2)));
typedef uint32_t u32x4 __attribute__((ext_vector_type(4)));

DEV u16 f2bf(float f) {
  union { float f; uint32_t u; } a; a.f = f;
  uint32_t u = a.u + 0x7fffu + ((a.u >> 16) & 1u);
  return (u16)(u >> 16);
}
DEV float b2f(u16 v) {
  union { uint32_t u; float f; } a; a.u = ((uint32_t)v) << 16;
  return a.f;
}

DEV float fexp2(float x) {
#if __has_builtin(__builtin_amdgcn_exp2f)
  return __builtin_amdgcn_exp2f(x);
#else
  return __expf(x * 0.69314718056f);
#endif
}

DEV uint32_t cvtpk(float lo, float hi) {
  uint32_t r;
  asm("v_cvt_pk_bf16_f32 %0, %1, %2" : "=v"(r) : "v"(lo), "v"(hi));
  return r;
}

DEV void gload16(const void* g, void* lds) {
  __builtin_amdgcn_global_load_lds((__attribute__((address_space(1))) void*)g,
                                   (__attribute__((address_space(3))) void*)lds,
                                   16, 0, 0);
}

// ---------------- weight convert + transpose: dst[n][k] = bf16(src[k][n]) ----
struct TMat { const float* src; u16* dst; int K; int N; int t0; };
struct TArgs { TMat m[26]; int nmat; };

__global__ __launch_bounds__(256) void transpose_all(TArgs args) {
  __shared__ float tile[128][65];
  const int bid = blockIdx.x;
  int i = 0;
  #pragma unroll 1
  for (int t = 1; t < args.nmat; ++t) if (bid >= args.m[t].t0) i = t;
  const TMat mm = args.m[i];
  const int tid = threadIdx.x;
  const int tix = bid - mm.t0;
  const int ntx = mm.N >> 6;
  const int n0 = (tix % ntx) << 6, k0 = (tix / ntx) << 7;
  const int lr = tid >> 4, lc4 = (tid & 15) << 2;
  #pragma unroll
  for (int p = 0; p < 8; ++p) {
    const int r = lr + (p << 4);
    f32x4 v = __builtin_nontemporal_load(
        (const f32x4*)(mm.src + (size_t)(k0 + r) * mm.N + n0 + lc4));
    *(f32x4*)&tile[r][lc4] = v;
  }
  __syncthreads();
  const int ks8 = (tid & 15) << 3;
  #pragma unroll
  for (int p = 0; p < 4; ++p) {
    const int n = (tid >> 4) + (p << 4);
    float v[8];
    #pragma unroll
    for (int u = 0; u < 8; ++u) v[u] = tile[ks8 + u][n];
    u32x4 o;
    o[0] = cvtpk(v[0], v[1]); o[1] = cvtpk(v[2], v[3]);
    o[2] = cvtpk(v[4], v[5]); o[3] = cvtpk(v[6], v[7]);
    __builtin_nontemporal_store(
        o, (u32x4*)(mm.dst + (size_t)(n0 + n) * mm.K + k0 + ks8));
  }
}

// ---------------- fp32 -> bf16 convert (x_in -> xb) --------------------------
__global__ __launch_bounds__(256) void f2b_kernel(const f32x4* __restrict__ in,
                                                  u32x4* __restrict__ out, int n8) {
  const int i = blockIdx.x * 256 + threadIdx.x;
  if (i >= n8) return;
  f32x4 a = __builtin_nontemporal_load(in + 2 * i);
  f32x4 b = __builtin_nontemporal_load(in + 2 * i + 1);
  u32x4 o;
  o[0] = cvtpk(a[0], a[1]); o[1] = cvtpk(a[2], a[3]);
  o[2] = cvtpk(b[0], b[1]); o[3] = cvtpk(b[2], b[3]);
  __builtin_nontemporal_store(o, out + i);
}

// ---------------- LayerNorm: bf16 in -> bf16 out, XCD-aligned tokens --------
__global__ __launch_bounds__(256) void ln_kernel(const u16* __restrict__ x,
                                                 const float* __restrict__ sc,
                                                 const float* __restrict__ bi,
                                                 u16* __restrict__ y, int Mtok) {
  const int bid = blockIdx.x;
  const int tok = ((bid & 7) << 10) + ((bid >> 3) << 2) + (threadIdx.x >> 6);
  const int l = threadIdx.x & 63;
  if (tok >= Mtok) return;
  const u16* row = x + (size_t)tok * 768;
  u16x8 v0 = *(const u16x8*)(row + l * 8);
  u16x4 v1 = *(const u16x4*)(row + 512 + l * 4);
  float f[12];
  #pragma unroll
  for (int i = 0; i < 8; ++i) f[i] = b2f(v0[i]);
  #pragma unroll
  for (int i = 0; i < 4; ++i) f[8 + i] = b2f(v1[i]);
  float s = 0.f, q = 0.f;
  #pragma unroll
  for (int i = 0; i < 12; ++i) { s += f[i]; q += f[i] * f[i]; }
  #pragma unroll
  for (int off = 1; off < 64; off <<= 1) { s += __shfl_xor(s, off); q += __shfl_xor(q, off); }
  const float mean = s * (1.f / 768.f);
  const float var = q * (1.f / 768.f) - mean * mean;
  const float r = rsqrtf(var + 1e-6f);
  float4 s0 = *(const float4*)(sc + l * 8);
  float4 s1 = *(const float4*)(sc + l * 8 + 4);
  float4 s2 = *(const float4*)(sc + 512 + l * 4);
  float4 b0 = *(const float4*)(bi + l * 8);
  float4 b1 = *(const float4*)(bi + l * 8 + 4);
  float4 b2 = *(const float4*)(bi + 512 + l * 4);
  float g[12];
  g[0] = (f[0]-mean)*r*s0.x + b0.x;  g[1] = (f[1]-mean)*r*s0.y + b0.y;
  g[2] = (f[2]-mean)*r*s0.z + b0.z;  g[3] = (f[3]-mean)*r*s0.w + b0.w;
  g[4] = (f[4]-mean)*r*s1.x + b1.x;  g[5] = (f[5]-mean)*r*s1.y + b1.y;
  g[6] = (f[6]-mean)*r*s1.z + b1.z;  g[7] = (f[7]-mean)*r*s1.w + b1.w;
  g[8] = (f[8]-mean)*r*s2.x + b2.x;  g[9] = (f[9]-mean)*r*s2.y + b2.y;
  g[10] = (f[10]-mean)*r*s2.z + b2.z; g[11] = (f[11]-mean)*r*s2.w + b2.w;
  u16* yr = y + (size_t)tok * 768;
  u32x4 o;
  o[0] = cvtpk(g[0], g[1]); o[1] = cvtpk(g[2], g[3]);
  o[2] = cvtpk(g[4], g[5]); o[3] = cvtpk(g[6], g[7]);
  *(u32x4*)(yr + l * 8) = o;
  u32x2 o2; o2[0] = cvtpk(g[8], g[9]); o2[1] = cvtpk(g[10], g[11]);
  *(u32x2*)(yr + 512 + l * 4) = o2;
}

// ---------------- bf16 GEMM 128x128, BK=64, 16 waves, counted-vmcnt ---------
// Wave tile 32x32 (acc 2x2). 1024 threads; 2 blocks/CU = 32 waves/CU (HW cap).
enum { EPI_BF16 = 0, EPI_RESID = 1, EPI_GELU = 2, EPI_RELU = 3 };

__global__ __launch_bounds__(1024, 2) void gemm128(
    const u16* __restrict__ A, const u16* __restrict__ Bt,
    const float* __restrict__ bias, const u16* __restrict__ residB,
    u16* __restrict__ outB, int N, int K, int nxb, int epi) {
  __shared__ u16 smem[32768];   // As[2][8192] @ 0, Bs[2][8192] @ 16384
  const int tid = threadIdx.x;
  const int w = tid >> 6, l = tid & 63;

  const int nwg = gridDim.x;
  const int flat = blockIdx.x;
  const int wg = (flat & 7) * (nwg >> 3) + (flat >> 3);
  const int bx = wg % nxb, by = wg / nxb;
  const int m0 = by << 7, n0 = bx << 7;

  const int wr = (w >> 2) << 5;          // 0,32,64,96
  const int wc = (w & 3) << 5;           // 0,32,64,96
  const int cl = l & 15, g = l >> 4;
  f32x4 acc[2][2] = {};

  // staging: wave w stages A rows [w*8,w*8+8) and B rows same; 1 gload each.
  const int lrow = l >> 3;               // 0..7; row&7 == lrow (8-aligned base)
  const int scol = ((l & 7) ^ lrow) << 3;
  const u16* agp = A  + (size_t)(m0 + (w << 3) + lrow) * K + scol;
  const u16* bgp = Bt + (size_t)(n0 + (w << 3) + lrow) * K + scol;
  const int ldso = w << 9;               // 8 rows x 64 elems
  const int nkt = K >> 6;

  gload16(agp, &smem[ldso]);
  gload16(bgp, &smem[16384 + ldso]);

  const int sw = cl & 7;
  for (int kt = 0; kt < nkt; ++kt) {
    const int cur = kt & 1;
    if (kt + 1 < nkt) {
      const size_t koff = (size_t)(kt + 1) << 6;
      const int nb = (cur ^ 1) << 13;
      gload16(agp + koff, &smem[nb + ldso]);
      gload16(bgp + koff, &smem[16384 + nb + ldso]);
      asm volatile("s_waitcnt vmcnt(2)" ::: "memory");
    } else {
      asm volatile("s_waitcnt vmcnt(0)" ::: "memory");
    }
    __builtin_amdgcn_s_barrier();
    __builtin_amdgcn_sched_barrier(0);
    const u16* Ab = &smem[cur << 13];
    const u16* Bb = &smem[16384 + (cur << 13)];
    #pragma unroll
    for (int ks = 0; ks < 2; ++ks) {
      bf16x8 af[2], bfr[2];
      const int ps = (((ks << 2) | g) ^ sw) << 3;
      #pragma unroll
      for (int mt = 0; mt < 2; ++mt)
        af[mt] = *(const bf16x8*)(Ab + ((wr + mt * 16 + cl) << 6) + ps);
      #pragma unroll
      for (int nt = 0; nt < 2; ++nt)
        bfr[nt] = *(const bf16x8*)(Bb + ((wc + nt * 16 + cl) << 6) + ps);
      #pragma unroll
      for (int mt = 0; mt < 2; ++mt)
        #pragma unroll
        for (int nt = 0; nt < 2; ++nt)
          acc[mt][nt] = __builtin_amdgcn_mfma_f32_16x16x32_bf16(af[mt], bfr[nt], acc[mt][nt], 0, 0, 0);
    }
    asm volatile("s_waitcnt lgkmcnt(0)" ::: "memory");
    __builtin_amdgcn_s_barrier();
  }

  // epilogue: per-wave LDS transpose (16x34 fp32) -> coalesced bf16 stores
  float* scr = (float*)smem + w * 544;
  const int rg = g << 2;
  const int er = l >> 2;                 // 0..15
  const int ec0 = (l & 3) << 3;          // 0,8,16,24
  #pragma unroll
  for (int mt = 0; mt < 2; ++mt) {
    #pragma unroll
    for (int nt = 0; nt < 2; ++nt)
      #pragma unroll
      for (int j = 0; j < 4; ++j)
        scr[(rg + j) * 34 + nt * 16 + cl] = acc[mt][nt][j];
    const int grow = m0 + wr + mt * 16 + er;
    const int gcol = n0 + wc + ec0;
    float v[8];
    #pragma unroll
    for (int u = 0; u < 8; ++u) v[u] = scr[er * 34 + ec0 + u];
    if (bias) {
      #pragma unroll
      for (int u = 0; u < 8; ++u) v[u] += bias[gcol + u];
    }
    if (epi == EPI_RESID) {
      u16x8 rv = *(const u16x8*)(residB + (size_t)grow * N + gcol);
      #pragma unroll
      for (int u = 0; u < 8; ++u) v[u] += b2f(rv[u]);
    } else if (epi == EPI_GELU) {
      #pragma unroll
      for (int u = 0; u < 8; ++u) {
        const float x = v[u];
        const float e = __expf(-(1.5957691216f * x + 0.0713548163f * x * x * x));
        v[u] = x / (1.f + e);
      }
    } else if (epi == EPI_RELU) {
      #pragma unroll
      for (int u = 0; u < 8; ++u) v[u] = fmaxf(v[u], 0.f);
    }
    u32x4 ov;
    ov[0] = cvtpk(v[0], v[1]); ov[1] = cvtpk(v[2], v[3]);
    ov[2] = cvtpk(v[4], v[5]); ov[3] = cvtpk(v[6], v[7]);
    u32x4* op = (u32x4*)(outB + (size_t)grow * N + gcol);
    if (epi == EPI_BF16 || epi == EPI_GELU)
      __builtin_nontemporal_store(ov, op);
    else
      *op = ov;
  }
}

// ---------------- flash attention (causal + ALiBi), XCD-chunked, balanced ----
__global__ __launch_bounds__(512, 6) void attn_kernel(const u16* __restrict__ qkv,
                                                      u16* __restrict__ o) {
  __shared__ u16 Ksm[2][4096];
  __shared__ u16 Vt[2][64][68];
  __shared__ u16 P[8][16][72];
  const int flat = blockIdx.x;
  const int b = flat & 7;
  const int rr = flat >> 3;
  const int h = rr >> 3;
  const int j = rr & 7;
  const int tid = threadIdx.x;
  const int w = tid >> 6, l = tid & 63;
  const int cl = l & 15, lg = l >> 4;
  const int qtile = (w < 4) ? j : 15 - j;
  const int q0 = qtile * 64 + (w & 3) * 16;
  const int rowg = q0 + cl;
  const float log2e = 1.44269504f;
  const float scale2 = 0.125f * log2e;
  const float slope = (h < 8) ? exp2f(-(float)(h + 1)) : exp2f(-0.5f - (float)(h - 8));
  const float slope2 = slope * log2e;
  const size_t rs_ = 2304;
  const size_t bbase = (size_t)b * 1024 * rs_;

  const u16* qp = qkv + bbase + (size_t)rowg * rs_ + h * 64 + lg * 8;
  bf16x8 qa0 = *(const bf16x8*)qp;
  bf16x8 qa1 = *(const bf16x8*)(qp + 32);

  float m_r = -1e30f, l_r = 0.f;
  f32x4 oacc[4];
  #pragma unroll
  for (int d = 0; d < 4; ++d) oacc[d] = (f32x4){0.f, 0.f, 0.f, 0.f};

  const u16* ksrc = qkv + bbase + (size_t)(tid >> 3) * rs_ + 768 + h * 64 +
                    (((tid & 7) ^ ((tid >> 3) & 7)) << 3);
  const int vd0 = w << 3;
  const u16* vbase = qkv + bbase + (size_t)l * rs_ + 1536 + h * 64 + vd0;

  const int nkv = 16 - j;
  gload16(ksrc, &Ksm[0][w << 9]);
  u16x8 vreg = *(const u16x8*)vbase;
  __syncthreads();

  const int sw = cl & 7;
  const int ps0 = (lg ^ sw) << 3;
  const int ps1 = ps0 ^ 32;

  for (int kv = 0; kv < nkv; ++kv) {
    const int buf = kv & 1;
    #pragma unroll
    for (int i = 0; i < 8; ++i) Vt[buf][vd0 + i][l] = vreg[i];
    u16x8 vnext = vreg;
    if (kv + 1 < nkv) {
      gload16(ksrc + (size_t)(kv + 1) * 64 * rs_, &Ksm[buf ^ 1][w << 9]);
      vnext = *(const u16x8*)(vbase + (size_t)(kv + 1) * 64 * rs_);
    }

    const bool active = (kv <= qtile);
    bf16x8 pa0, pa1;
    if (active) {
      const u16* Kb = &Ksm[buf][0];
      f32x4 pp[4];
      float pm = -3.0e38f;
      __builtin_amdgcn_s_setprio(1);
      #pragma unroll
      for (int nt = 0; nt < 4; ++nt) {
        const int row = nt * 16 + cl;
        bf16x8 bk0 = *(const bf16x8*)(Kb + (row << 6) + ps0);
        bf16x8 bk1 = *(const bf16x8*)(Kb + (row << 6) + ps1);
        f32x4 s = (f32x4){0.f, 0.f, 0.f, 0.f};
        s = __builtin_amdgcn_mfma_f32_16x16x32_bf16(bk0, qa0, s, 0, 0, 0);
        s = __builtin_amdgcn_mfma_f32_16x16x32_bf16(bk1, qa1, s, 0, 0, 0);
        const int kb = kv * 64 + nt * 16 + (lg << 2);
        #pragma unroll
        for (int jj = 0; jj < 4; ++jj) {
          const int colg = kb + jj;
          float v = s[jj] * scale2 + slope2 * (float)colg;
          pp[nt][jj] = (colg <= rowg) ? v : -3.0e38f;
        }
        pm = fmaxf(pm, fmaxf(fmaxf(pp[nt][0], pp[nt][1]),
                             fmaxf(pp[nt][2], pp[nt][3])));
      }
      __builtin_amdgcn_s_setprio(0);
      pm = fmaxf(pm, __shfl_xor(pm, 16));
      pm = fmaxf(pm, __shfl_xor(pm, 32));
      if (!__all(pm <= m_r + 11.54f)) {
        const float mnew = fmaxf(m_r, pm);
        const float al = fexp2(m_r - mnew);
        m_r = mnew;
        l_r *= al;
        float a4[4];
        #pragma unroll
        for (int jj = 0; jj < 4; ++jj) a4[jj] = __shfl(al, (lg << 2) + jj);
        #pragma unroll
        for (int d = 0; d < 4; ++d)
          #pragma unroll
          for (int jj = 0; jj < 4; ++jj) oacc[d][jj] *= a4[jj];
      }
      float rs = 0.f;
      #pragma unroll
      for (int nt = 0; nt < 4; ++nt) {
        #pragma unroll
        for (int jj = 0; jj < 4; ++jj) {
          float p = fexp2(pp[nt][jj] - m_r);
          pp[nt][jj] = p;
          rs += p;
        }
      }
      rs += __shfl_xor(rs, 16);
      rs += __shfl_xor(rs, 32);
      l_r += rs;
      #pragma unroll
      for (int nt = 0; nt < 4; ++nt) {
        u32x2 pr;
        pr[0] = cvtpk(pp[nt][0], pp[nt][1]);
        pr[1] = cvtpk(pp[nt][2], pp[nt][3]);
        *(u32x2*)&P[w][cl][nt * 16 + (lg << 2)] = pr;
      }
      pa0 = *(const bf16x8*)&P[w][cl][lg * 8];
      pa1 = *(const bf16x8*)&P[w][cl][32 + lg * 8];
    }

    __syncthreads();

    if (active) {
      __builtin_amdgcn_s_setprio(1);
      #pragma unroll
      for (int d = 0; d < 4; ++d) {
        bf16x8 bv0 = *(const bf16x8*)&Vt[buf][d * 16 + cl][lg * 8];
        bf16x8 bv1 = *(const bf16x8*)&Vt[buf][d * 16 + cl][32 + lg * 8];
        oacc[d] = __builtin_amdgcn_mfma_f32_16x16x32_bf16(pa0, bv0, oacc[d], 0, 0, 0);
        oacc[d] = __builtin_amdgcn_mfma_f32_16x16x32_bf16(pa1, bv1, oacc[d], 0, 0, 0);
      }
      __builtin_amdgcn_s_setprio(0);
    }
    vreg = vnext;
  }

  const float linv = 1.f / l_r;
  float i4[4];
  #pragma unroll
  for (int jj = 0; jj < 4; ++jj) i4[jj] = __shfl(linv, (lg << 2) + jj);
  u16* op = o + ((size_t)b * 1024 + q0) * 768 + h * 64;
  #pragma unroll
  for (int d = 0; d < 4; ++d)
    #pragma unroll
    for (int jj = 0; jj < 4; ++jj)
      op[(size_t)((lg << 2) + jj) * 768 + d * 16 + cl] = f2bf(oacc[d][jj] * i4[jj]);
}

// ---------------- action head: out[M,7] = act[M,768] @ w[768,7] --------------
__global__ __launch_bounds__(256) void head2_kernel(const u16* __restrict__ act,
                                                    const float* __restrict__ w,
                                                    float* __restrict__ out, int Mtok) {
  const int bid = blockIdx.x;
  const int tok = ((bid & 7) << 10) + ((bid >> 3) << 2) + (threadIdx.x >> 6);
  const int l = threadIdx.x & 63;
  if (tok >= Mtok) return;
  float s[7] = {0.f, 0.f, 0.f, 0.f, 0.f, 0.f, 0.f};
  const u16* ar = act + (size_t)tok * 768;
  #pragma unroll
  for (int i = 0; i < 12; ++i) {
    const int k = l + i * 64;
    const float a = b2f(ar[k]);
    #pragma unroll
    for (int j = 0; j < 7; ++j) s[j] += a * w[k * 7 + j];
  }
  #pragma unroll
  for (int off = 32; off; off >>= 1)
    #pragma unroll
    for (int j = 0; j < 7; ++j) s[j] += __shfl_down(s[j], off);
  if (l == 0) {
    #pragma unroll
    for (int j = 0; j < 7; ++j) out[(size_t)tok * 7 + j] = s[j];
  }
}

// ---------------- orchestration ---------------------------------------------
extern "C" void kernel_launch(void* const* d_in, const int* in_sizes, int n_in,
                              void* d_out, int out_size, void* d_ws, size_t ws_size,
                              hipStream_t stream) {
  const float* x_in = (const float*)d_in[0];
  const float* ln1s = (const float*)d_in[1];
  const float* ln1b = (const float*)d_in[2];
  const float* wqkv = (const float*)d_in[3];
  const float* bqkv = (const float*)d_in[4];
  const float* wo   = (const float*)d_in[5];
  const float* bo   = (const float*)d_in[6];
  const float* ln2s = (const float*)d_in[7];
  const float* ln2b = (const float*)d_in[8];
  const float* w1   = (const float*)d_in[9];
  const float* w2   = (const float*)d_in[10];
  const float* lnfs = (const float*)d_in[11];
  const float* lnfb = (const float*)d_in[12];
  const float* hw1  = (const float*)d_in[13];
  const float* hb1  = (const float*)d_in[14];
  const float* hw2  = (const float*)d_in[15];
  float* out = (float*)d_out;

  const int Mtok = 8192, E = 768, E3 = 2304, F = 3072, DEPTH = 6;

  char* ws = (char*)d_ws;
  size_t off = 0;
  auto alloc = [&](size_t bytes) -> char* {
    char* p = ws + off; off += (bytes + 255) & ~(size_t)255; return p;
  };
  u16*  wqkvt = (u16*)alloc((size_t)DEPTH * E3 * E * 2);
  u16*  wot   = (u16*)alloc((size_t)DEPTH * E * E * 2);
  u16*  w1t   = (u16*)alloc((size_t)DEPTH * F * E * 2);
  u16*  w2t   = (u16*)alloc((size_t)DEPTH * E * F * 2);
  u16*  hw1t  = (u16*)alloc((size_t)E * E * 2);
  u16*  xb    = (u16*)alloc((size_t)Mtok * E * 2);
  u16*  yb    = (u16*)alloc((size_t)Mtok * E * 2);
  u16*  big   = (u16*)alloc((size_t)Mtok * F * 2);
  (void)ws_size; (void)in_sizes; (void)n_in; (void)out_size;

  TArgs ta; int nm = 0; int t0 = 0;
  auto add = [&](const float* s, u16* d, int K, int N) {
    ta.m[nm].src = s; ta.m[nm].dst = d; ta.m[nm].K = K; ta.m[nm].N = N; ta.m[nm].t0 = t0;
    t0 += (N / 64) * (K / 128); ++nm;
  };
  for (int i = 0; i < DEPTH; ++i) add(wqkv + (size_t)i * E * E3, wqkvt + (size_t)i * E3 * E, E, E3);
  for (int i = 0; i < DEPTH; ++i) add(wo + (size_t)i * E * E, wot + (size_t)i * E * E, E, E);
  for (int i = 0; i < DEPTH; ++i) add(w1 + (size_t)i * E * F, w1t + (size_t)i * F * E, E, F);
  for (int i = 0; i < DEPTH; ++i) add(w2 + (size_t)i * F * E, w2t + (size_t)i * E * F, F, E);
  add(hw1, hw1t, E, E);
  ta.nmat = nm;
  transpose_all<<<t0, 256, 0, stream>>>(ta);

  f2b_kernel<<<(Mtok * E / 8 + 255) / 256, 256, 0, stream>>>(
      (const f32x4*)x_in, (u32x4*)xb, Mtok * E / 8);

  u16* qkvb = big;
  for (int i = 0; i < DEPTH; ++i) {
    ln_kernel<<<Mtok / 4, 256, 0, stream>>>(xb, ln1s + i * E, ln1b + i * E, yb, Mtok);
    gemm128<<<18 * 64, 1024, 0, stream>>>(yb, wqkvt + (size_t)i * E3 * E, bqkv + (size_t)i * E3,
                                          nullptr, qkvb, E3, E, 18, EPI_BF16);
    attn_kernel<<<768, 512, 0, stream>>>(qkvb, yb);
    gemm128<<<6 * 64, 1024, 0, stream>>>(yb, wot + (size_t)i * E * E, bo + (size_t)i * E,
                                         xb, xb, E, E, 6, EPI_RESID);
    ln_kernel<<<Mtok / 4, 256, 0, stream>>>(xb, ln2s + i * E, ln2b + i * E, yb, Mtok);
    gemm128<<<24 * 64, 1024, 0, stream>>>(yb, w1t + (size_t)i * F * E, nullptr,
                                          nullptr, big, F, E, 24, EPI_GELU);
    gemm128<<<6 * 64, 1024, 0, stream>>>(big, w2t + (size_t)i * E * F, nullptr,
                                         xb, xb, E, F, 6, EPI_RESID);
  }
  ln_kernel<<<Mtok / 4, 256, 0, stream>>>(xb, lnfs, lnfb, yb, Mtok);
  gemm128<<<6 * 64, 1024, 0, stream>>>(yb, hw1t, hb1, nullptr, big,
                                       E, E, 6, EPI_RELU);
  head2_kernel<<<Mtok / 4, 256, 0, stream>>>(big, hw2, out, Mtok);
}